// Round 10
// baseline (886.883 us; speedup 1.0000x reference)
//
#include <hip/hip_runtime.h>
#include <hip/hip_bf16.h>

// LSTM encoder, single fused kernel (producer/consumer).
//   Grid = 256 WGs x 256 thr. WGs 0-63: persistent recurrence, one batch row
//   each. WGs 64-255: xg producers, 8 timesteps per chunk (256 chunks),
//   publishing via agent-scope release flags in d_ws.
// Consumer: 4 waves; lane = (col, K-half). 64 v_dot4_i32_i8 per lane; K-half
//   partials merge via DPP quad_perm add (exact i32, no LDS). Activation
//   SPLIT across the kh pair: kh0 does sig(i),tanh(g); kh1 does sig(f),sig(o);
//   2 DPP float exchanges rebuild the full cell in both lanes (identical
//   bits). One lgkmcnt-only barrier/step; h ping-pong = 128 B LDS; xg
//   prefetched in 8-step register chunks with distance-2 flag pipelining.
// Fallback single kernel if ws_size too small.

namespace {

constexpr int T_LEN  = 2048;
constexpr int Bsz    = 64;
constexpr int Dd     = 128;
constexpr int Hh     = 128;
constexpr int Gg     = 512;
constexpr int XS     = 136;    // bf16 LDS row stride (producer A-tile / fallback)
constexpr int NCHUNK = 256;    // 8 timesteps per chunk
constexpr int CONS   = 64;     // consumer WGs (one per batch row)
constexpr int PROD   = 192;    // producer WGs
constexpr unsigned int SENT = 0x5EC7C0DEu;

typedef __attribute__((ext_vector_type(8))) short   short8;
typedef __attribute__((ext_vector_type(4))) float   floatx4;
typedef __attribute__((ext_vector_type(4))) int     intx4;
typedef __attribute__((ext_vector_type(2))) unsigned int uintx2;

#define MFMA16(a, b, c) __builtin_amdgcn_mfma_f32_16x16x32_bf16((a), (b), (c), 0, 0, 0)

#if __has_builtin(__builtin_amdgcn_sdot4)
__device__ __forceinline__ int dot4i8(int a, int b, int c) {
    return __builtin_amdgcn_sdot4(a, b, c, false);
}
#else
__device__ __forceinline__ int dot4i8(int a, int b, int c) {
#pragma unroll
    for (int j = 0; j < 4; ++j)
        c += ((a << (24 - 8 * j)) >> 24) * ((b << (24 - 8 * j)) >> 24);
    return c;
}
#endif

// value from partner lane^1 (quad_perm [1,0,3,2]) -- full-rate VALU
__device__ __forceinline__ int xor1_i(int v) {
    return __builtin_amdgcn_mov_dpp(v, 0xB1, 0xF, 0xF, true);
}
__device__ __forceinline__ float xor1_f(float v) {
    union { float f; int i; } u; u.f = v;
    u.i = __builtin_amdgcn_mov_dpp(u.i, 0xB1, 0xF, 0xF, true);
    return u.f;
}

__device__ __forceinline__ float sigmoidf_(float x) {
    return __builtin_amdgcn_rcpf(1.0f + __builtin_amdgcn_exp2f(x * -1.44269504f));
}
__device__ __forceinline__ float tanhf_(float x) {
    return __builtin_fmaf(-2.0f,
        __builtin_amdgcn_rcpf(1.0f + __builtin_amdgcn_exp2f(x * 2.88539008f)), 1.0f);
}
__device__ __forceinline__ unsigned short f2bf(float f) {
    __hip_bfloat16 h = __float2bfloat16(f);  // RNE
    union { __hip_bfloat16 b; unsigned short u; } v; v.b = h; return v.u;
}
__device__ __forceinline__ float fi_(unsigned int u) {
    union { unsigned int u; float f; } v; v.u = u; return v.f;
}
__device__ __forceinline__ uintx2 f4bf(const float4 v) {
    union { unsigned short us[4]; uintx2 u2; } p;
    p.us[0] = f2bf(v.x); p.us[1] = f2bf(v.y); p.us[2] = f2bf(v.z); p.us[3] = f2bf(v.w);
    return p.u2;
}
__device__ __forceinline__ short8 ld8bf(const float* p) {
    const float4 a = *reinterpret_cast<const float4*>(p);
    const float4 b = *reinterpret_cast<const float4*>(p + 4);
    short8 s;
    s[0] = (short)f2bf(a.x); s[1] = (short)f2bf(a.y);
    s[2] = (short)f2bf(a.z); s[3] = (short)f2bf(a.w);
    s[4] = (short)f2bf(b.x); s[5] = (short)f2bf(b.y);
    s[6] = (short)f2bf(b.z); s[7] = (short)f2bf(b.w);
    return s;
}
// barrier without the compiler's vmcnt(0) drain: LDS-visibility only
__device__ __forceinline__ void lds_barrier() {
    asm volatile("s_waitcnt lgkmcnt(0)\n\ts_barrier" ::: "memory");
}
__device__ __forceinline__ void wait_chunk(const unsigned int* flags, int k) {
    while (__hip_atomic_load(&flags[k], __ATOMIC_RELAXED,
                             __HIP_MEMORY_SCOPE_AGENT) != SENT)
        __builtin_amdgcn_s_sleep(2);
    __builtin_amdgcn_fence(__ATOMIC_ACQUIRE, "agent");
}

// =================== fused producer/consumer kernel ==========================
__global__ __launch_bounds__(256) void lstm_fused_all(
    const int*   __restrict__ tokens,
    const float* __restrict__ emb,
    const float* __restrict__ Wih,
    const float* __restrict__ Whh,
    const float* __restrict__ bih,
    const float* __restrict__ bhh,
    unsigned short* __restrict__ xg,     // [T][64][128][4] bf16, in d_ws
    unsigned int*   __restrict__ flags,  // [NCHUNK], in d_ws after xg
    float*       __restrict__ out)       // [2][64][128] fp32
{
    __shared__ __align__(16) unsigned short albs[2][64 * XS];  // producer A-tile

    const int tid = threadIdx.x;

    if (blockIdx.x < CONS) {
        // ================= CONSUMER: one batch row ===========================
        signed char (*hbuf)[128] =
            reinterpret_cast<signed char (*)[128]>(&albs[0][0]);  // [2][128]

        const int wv = tid >> 6;          // wave 0..3
        const int l  = tid & 63;
        const int kh = l & 1;             // K half (0: k<64, 1: k>=64)
        const int c  = wv * 32 + (l >> 1);  // hidden column
        const int b  = blockIdx.x;        // batch row

        // Whh rows {g*128+c} -> i8 (full-row scale; quantize own K-half)
        int   wq[4][16];
        float dq[4];
#pragma unroll
        for (int g = 0; g < 4; ++g) {
            const float* wr = Whh + (size_t)(g * 128 + c) * Hh;
            float am = 0.f;
#pragma unroll 8
            for (int k = 0; k < 128; k += 4) {
                const float4 v = *reinterpret_cast<const float4*>(wr + k);
                am = fmaxf(am, fmaxf(fmaxf(fabsf(v.x), fabsf(v.y)),
                                     fmaxf(fabsf(v.z), fabsf(v.w))));
            }
            const float swm = fmaxf(am, 1e-20f);
            dq[g] = swm * (1.0f / (127.0f * 127.0f));
            const float inv = 127.0f / swm;
#pragma unroll
            for (int d = 0; d < 16; ++d) {
                const float4 v =
                    *reinterpret_cast<const float4*>(wr + kh * 64 + d * 4);
                const int b0 = (int)__builtin_rintf(v.x * inv);
                const int b1 = (int)__builtin_rintf(v.y * inv);
                const int b2 = (int)__builtin_rintf(v.z * inv);
                const int b3 = (int)__builtin_rintf(v.w * inv);
                wq[g][d] = (b0 & 0xff) | ((b1 & 0xff) << 8) |
                           ((b2 & 0xff) << 16) | ((b3 & 0xff) << 24);
            }
        }

        // per-lane act-split constants:
        //   kh0 owns gates i (sigmoid) and g (tanh); kh1 owns f,o (sigmoid)
        const float dqA = kh ? dq[1] : dq[0];
        const float dqB = kh ? dq[3] : dq[2];
        const float cB  = kh ? -1.44269504f : 2.88539008f;  // B nonlinearity arg scale
        const unsigned int shA = kh ? 0u : 16u;             // xg unpack shift

        // h(0) = 0 in regs (buffers always written before read)
        intx4 hv[4];
#pragma unroll
        for (int j = 0; j < 4; ++j) hv[j] = (intx4){0, 0, 0, 0};

        const unsigned short* xptr = xg + (size_t)b * Gg + c * 4;
        const size_t xstride = (size_t)Bsz * Gg;

        // startup: verify chunks 0 and 1; load chunk 0
        wait_chunk(flags, 0);
        uintx2 xc[8], xcn[8];
#pragma unroll
        for (int u = 0; u < 8; ++u)
            xc[u] = *reinterpret_cast<const uintx2*>(xptr + (size_t)u * xstride);
        wait_chunk(flags, 1);

        float c_state = 0.0f;
        float h_last  = 0.0f;

        for (int g = 0; g < NCHUNK; ++g) {
#pragma unroll
            for (int s = 0; s < 8; ++s) {
                if (s == 0) {
                    // flag[g+1] verified a chunk ago -> load immediately
                    int tn = g + 1;
                    if (tn >= NCHUNK) tn = 0;       // dummy re-load of chunk 0
                    const size_t tb = (size_t)tn * 8;
#pragma unroll
                    for (int u = 0; u < 8; ++u)
                        xcn[u] = *reinterpret_cast<const uintx2*>(
                            xptr + (tb + u) * xstride);
                    // distance-2: verify flag for the NEXT chunk's loads
                    if (g + 2 < NCHUNK) wait_chunk(flags, g + 2);
                }

                // half-gates: 64 sdot4 (exact i32)
                int a0 = 0, a1 = 0, a2 = 0, a3 = 0;
#pragma unroll
                for (int j = 0; j < 4; ++j) {
#pragma unroll
                    for (int e = 0; e < 4; ++e) {
                        const int hd = hv[j][e];
                        const int d  = j * 4 + e;
                        a0 = dot4i8(wq[0][d], hd, a0);
                        a1 = dot4i8(wq[1][d], hd, a1);
                        a2 = dot4i8(wq[2][d], hd, a2);
                        a3 = dot4i8(wq[3][d], hd, a3);
                    }
                }
                // merge K-halves with partner lane^1 (DPP, no LDS)
                const int m0 = a0 + xor1_i(a0);
                const int m1 = a1 + xor1_i(a1);
                const int m2 = a2 + xor1_i(a2);
                const int m3 = a3 + xor1_i(a3);

                // this lane's two gates
                const int gA = kh ? m1 : m0;        // i | f
                const int gB = kh ? m3 : m2;        // g | o
                const uintx2 xv = xc[s];
                const float xA = fi_((xv.x << shA) & 0xffff0000u);
                const float xB = fi_((xv.y << shA) & 0xffff0000u);
                const float vA = __builtin_fmaf((float)gA, dqA, xA);
                const float vB = __builtin_fmaf((float)gB, dqB, xB);

                // A is always a sigmoid; B is tanh (kh0) or sigmoid (kh1)
                const float nA = __builtin_amdgcn_rcpf(
                    1.0f + __builtin_amdgcn_exp2f(vA * -1.44269504f));
                const float rB = __builtin_amdgcn_rcpf(
                    1.0f + __builtin_amdgcn_exp2f(vB * cB));
                const float tB = __builtin_fmaf(-2.0f, rB, 1.0f);
                const float nB = kh ? rB : tB;

                // exchange nonlinear outputs with partner
                const float oA = xor1_f(nA);
                const float oB = xor1_f(nB);
                // kh0: si=nA tg=nB sf=oA so=oB ; kh1: si=oA tg=oB sf=nA so=nB
                const float sf   = kh ? nA : oA;
                const float so   = kh ? nB : oB;
                const float p1   = nA * nB;
                const float p2   = oA * oB;
                const float sitg = kh ? p2 : p1;    // si*tg, identical bits

                c_state = __builtin_fmaf(sf, c_state, sitg);
                h_last  = so * tanhf_(c_state);

                const int nxt = (s & 1) ^ 1;        // buffer parity of t+1
                if (kh == 0)
                    hbuf[nxt][c] =
                        (signed char)((int)__builtin_rintf(h_last * 127.0f));
                if (s == 7) {
#pragma unroll
                    for (int u = 0; u < 8; ++u) xc[u] = xcn[u];
                }
                lds_barrier();  // lgkm-only: h visible, vmem stays in flight
#pragma unroll
                for (int j = 0; j < 4; ++j)
                    hv[j] = *reinterpret_cast<const intx4*>(
                        &hbuf[nxt][kh * 64 + j * 16]);
            }
        }

        if (kh == 0) {
            out[b * Hh + c]            = h_last;
            out[Bsz * Hh + b * Hh + c] = c_state;
        }
    } else {
        // ================= PRODUCER: xg chunks of 8 timesteps ================
        const int pid  = blockIdx.x - CONS;
        const int wv   = tid >> 6;
        const int l    = tid & 63;
        const int quad = l >> 4;
        const int cl   = l & 15;
        const int srow = tid >> 2, sseg = tid & 3;   // staging: row, 32-col seg

        // bias for this lane's two hh columns (j = wv*2 + jj)
        float bias[2][4];
#pragma unroll
        for (int jj = 0; jj < 2; ++jj) {
            const int hhj = (wv * 2 + jj) * 16 + cl;
#pragma unroll
            for (int g = 0; g < 4; ++g)
                bias[jj][g] = bih[g * 128 + hhj] + bhh[g * 128 + hhj];
        }

        for (int chunk = pid; chunk < NCHUNK; chunk += PROD) {
            const int t0 = chunk * 8;

            {   // stage t0 into buf 0
                const int tok = tokens[srow * T_LEN + t0];
                const float* src = emb + (size_t)tok * Dd + sseg * 32;
#pragma unroll
                for (int p = 0; p < 4; ++p)
                    *reinterpret_cast<short8*>(
                        &albs[0][srow * XS + sseg * 32 + p * 8]) = ld8bf(src + p * 8);
            }
            __syncthreads();

            for (int tt = 0; tt < 8; ++tt) {
                const int cur = tt & 1, nxt = cur ^ 1;
                if (tt < 7) {   // stage next t
                    const int tok = tokens[srow * T_LEN + t0 + tt + 1];
                    const float* src = emb + (size_t)tok * Dd + sseg * 32;
#pragma unroll
                    for (int p = 0; p < 4; ++p)
                        *reinterpret_cast<short8*>(
                            &albs[nxt][srow * XS + sseg * 32 + p * 8]) =
                            ld8bf(src + p * 8);
                }

                // A-fragments for all 4 m-tiles x 4 k-chunks
                short8 af[4][4];
#pragma unroll
                for (int m = 0; m < 4; ++m)
#pragma unroll
                    for (int k = 0; k < 4; ++k)
                        af[m][k] = *reinterpret_cast<const short8*>(
                            &albs[cur][(m * 16 + cl) * XS + k * 32 + quad * 8]);

                const int t = t0 + tt;
#pragma unroll
                for (int jj = 0; jj < 2; ++jj) {
                    const int hhj = (wv * 2 + jj) * 16 + cl;
                    floatx4 acc[4][4];  // [g][m]
#pragma unroll
                    for (int g = 0; g < 4; ++g)
#pragma unroll
                        for (int m = 0; m < 4; ++m)
                            acc[g][m] = (floatx4){0.f, 0.f, 0.f, 0.f};
#pragma unroll
                    for (int g = 0; g < 4; ++g) {
                        const int n = g * 128 + hhj;
                        short8 bf[4];
#pragma unroll
                        for (int k = 0; k < 4; ++k)
                            bf[k] = ld8bf(Wih + (size_t)n * Dd + k * 32 + quad * 8);
#pragma unroll
                        for (int k = 0; k < 4; ++k)
#pragma unroll
                            for (int m = 0; m < 4; ++m)
                                acc[g][m] = MFMA16(af[m][k], bf[k], acc[g][m]);
                    }
                    // pack 4 gates per (b-row) and store 8 B
#pragma unroll
                    for (int m = 0; m < 4; ++m) {
#pragma unroll
                        for (int r = 0; r < 4; ++r) {
                            const int brow = m * 16 + quad * 4 + r;
                            union { unsigned short us[4]; uintx2 u2; } p;
#pragma unroll
                            for (int g = 0; g < 4; ++g)
                                p.us[g] = f2bf(acc[g][m][r] + bias[jj][g]);
                            *reinterpret_cast<uintx2*>(
                                xg + ((size_t)t * Bsz + brow) * Gg + hhj * 4) =
                                p.u2;
                        }
                    }
                }
                __syncthreads();  // staged buf visible; stores drained (vmcnt0)
            }

            // release: all 256 threads' stores are complete (barrier drained)
            if (tid == 0) {
                __builtin_amdgcn_fence(__ATOMIC_RELEASE, "agent");
                __hip_atomic_store(&flags[chunk], SENT, __ATOMIC_RELAXED,
                                   __HIP_MEMORY_SCOPE_AGENT);
            }
        }
    }
}

// ---------------- Fallback (R2 working kernel) if ws too small ---------------
__global__ __launch_bounds__(512, 2) void lstm_fused_fb(
    const int*   __restrict__ tokens,
    const float* __restrict__ emb,
    const float* __restrict__ Wih,
    const float* __restrict__ Whh,
    const float* __restrict__ bih,
    const float* __restrict__ bhh,
    float*       __restrict__ out)
{
    __shared__ unsigned short xbuf[2][16 * XS];
    __shared__ unsigned short hbuf2[2][16 * XS];
    __shared__ float scratch[4 * Gg];

    const int tid  = threadIdx.x;
    const int w    = tid >> 6;
    const int l    = tid & 63;
    const int quad = l >> 4;
    const int cl   = l & 15;
    const int bbase = blockIdx.x * 4;
    const int rr = tid >> 7;
    const int hh = tid & 127;

    short8 wih[4][4], whh[4][4];
    float  bias[4];
#pragma unroll
    for (int q = 0; q < 4; ++q) {
        const int n = q * 128 + w * 16 + cl;
#pragma unroll
        for (int kk = 0; kk < 4; ++kk) {
            const int k0 = kk * 32 + quad * 8;
            wih[q][kk] = ld8bf(Wih + n * Dd + k0);
            whh[q][kk] = ld8bf(Whh + n * Hh + k0);
        }
        bias[q] = bih[n] + bhh[n];
    }

    for (int i = tid; i < 16 * XS; i += 512) {
        xbuf[0][i] = 0; xbuf[1][i] = 0; hbuf2[0][i] = 0; hbuf2[1][i] = 0;
    }

    const bool gact = (tid < 128);
    const int  gr = tid >> 5;
    const int  gp = tid & 31;
    float4 gdataf = {0.f, 0.f, 0.f, 0.f};
    if (gact) {
        const int tok = tokens[(bbase + gr) * T_LEN + 0];
        gdataf = *reinterpret_cast<const float4*>(emb + (size_t)tok * Dd + gp * 4);
    }
    __syncthreads();
    if (gact) *reinterpret_cast<uintx2*>(&xbuf[0][gr * XS + gp * 4]) = f4bf(gdataf);
    if (gact) {
        const int tok = tokens[(bbase + gr) * T_LEN + 1];
        gdataf = *reinterpret_cast<const float4*>(emb + (size_t)tok * Dd + gp * 4);
    }
    __syncthreads();

    const int afrag_el = cl * XS + quad * 8;

    floatx4 acc[4];
#pragma unroll
    for (int q = 0; q < 4; ++q) acc[q] = (floatx4){bias[q], bias[q], bias[q], bias[q]};
    {
        short8 xf[4];
#pragma unroll
        for (int kk = 0; kk < 4; ++kk)
            xf[kk] = *reinterpret_cast<const short8*>(&xbuf[0][afrag_el + kk * 32]);
#pragma unroll
        for (int kk = 0; kk < 4; ++kk)
#pragma unroll
            for (int q = 0; q < 4; ++q)
                acc[q] = MFMA16(xf[kk], wih[q][kk], acc[q]);
    }

    float c_state = 0.0f, h_last = 0.0f;

    for (int t = 0; t < T_LEN; ++t) {
        const int cur = t & 1, nxt = cur ^ 1;
        short8 hf[4];
#pragma unroll
        for (int kk = 0; kk < 4; ++kk)
            hf[kk] = *reinterpret_cast<const short8*>(&hbuf2[cur][afrag_el + kk * 32]);
        if (gact && (t + 1 < T_LEN))
            *reinterpret_cast<uintx2*>(&xbuf[nxt][gr * XS + gp * 4]) = f4bf(gdataf);
        if (gact && (t + 2 < T_LEN)) {
            const int tok = tokens[(bbase + gr) * T_LEN + (t + 2)];
            gdataf = *reinterpret_cast<const float4*>(emb + (size_t)tok * Dd + gp * 4);
        }
#pragma unroll
        for (int kk = 0; kk < 4; ++kk)
#pragma unroll
            for (int q = 0; q < 4; ++q)
                acc[q] = MFMA16(hf[kk], whh[q][kk], acc[q]);
        if (quad == 0) {
#pragma unroll
            for (int q = 0; q < 4; ++q) {
                const int n = q * 128 + w * 16 + cl;
#pragma unroll
                for (int r = 0; r < 4; ++r)
                    scratch[r * Gg + n] = acc[q][r];
            }
        }
        __syncthreads();
#pragma unroll
        for (int q = 0; q < 4; ++q) acc[q] = (floatx4){bias[q], bias[q], bias[q], bias[q]};
        if (t + 1 < T_LEN) {
            short8 xf[4];
#pragma unroll
            for (int kk = 0; kk < 4; ++kk)
                xf[kk] = *reinterpret_cast<const short8*>(&xbuf[nxt][afrag_el + kk * 32]);
#pragma unroll
            for (int kk = 0; kk < 4; ++kk)
#pragma unroll
                for (int q = 0; q < 4; ++q)
                    acc[q] = MFMA16(xf[kk], wih[q][kk], acc[q]);
        }
        {
            const float iv = scratch[rr * Gg + hh];
            const float fv = scratch[rr * Gg + 128 + hh];
            const float gv = scratch[rr * Gg + 256 + hh];
            const float ov = scratch[rr * Gg + 384 + hh];
            const float si = sigmoidf_(iv);
            const float sf = sigmoidf_(fv);
            const float so = sigmoidf_(ov);
            const float tg = tanhf_(gv);
            c_state = sf * c_state + si * tg;
            h_last  = so * tanhf_(c_state);
            hbuf2[nxt][rr * XS + hh] = f2bf(h_last);
        }
        __syncthreads();
    }

    const int ob = (bbase + rr) * Hh + hh;
    out[ob]            = h_last;
    out[Bsz * Hh + ob] = c_state;
}

}  // namespace

extern "C" void kernel_launch(void* const* d_in, const int* in_sizes, int n_in,
                              void* d_out, int out_size, void* d_ws, size_t ws_size,
                              hipStream_t stream) {
    (void)in_sizes; (void)n_in; (void)out_size;
    const int*   tokens = (const int*)d_in[0];
    const float* emb    = (const float*)d_in[1];
    const float* Wih    = (const float*)d_in[2];
    const float* Whh    = (const float*)d_in[3];
    const float* bih    = (const float*)d_in[4];
    const float* bhh    = (const float*)d_in[5];

    const size_t xg_bytes = (size_t)T_LEN * Bsz * Gg * sizeof(unsigned short);  // 134 MB
    const size_t need = xg_bytes + NCHUNK * sizeof(unsigned int);
    if (ws_size >= need) {
        unsigned short* xg    = (unsigned short*)d_ws;
        unsigned int*   flags = (unsigned int*)((char*)d_ws + xg_bytes);
        lstm_fused_all<<<CONS + PROD, 256, 0, stream>>>(
            tokens, emb, Wih, Whh, bih, bhh, xg, flags, (float*)d_out);
    } else {
        lstm_fused_fb<<<16, 512, 0, stream>>>(tokens, emb, Wih, Whh, bih, bhh,
                                              (float*)d_out);
    }
}

// Round 11
// 879.263 us; speedup vs baseline: 1.0087x; 1.0087x over previous
//
#include <hip/hip_runtime.h>
#include <hip/hip_bf16.h>

// LSTM encoder, single fused kernel (producer/consumer).
//   Grid = 256 WGs x 256 thr. WGs 0-63: persistent recurrence, one batch row
//   each. WGs 64-255: xg producers, 8 timesteps per chunk (256 chunks),
//   publishing via agent-scope release flags in d_ws.
// Consumer: 4 waves; lane = (col, K-half). 64 v_dot4_i32_i8 per lane in TWO
//   independent 8-deep chains per gate (halved dependence depth); K-half
//   partials merge via DPP quad_perm add (exact i32, no LDS). Each lane
//   computes the full LSTM cell (R9 structure -- act-split regressed, R10).
//   One lgkmcnt-only barrier/step; h ping-pong = 128 B LDS; xg prefetched in
//   8-step register chunks; chunk-flag poll at s==4 (off the load-burst slot).
// Fallback single kernel if ws_size too small.

namespace {

constexpr int T_LEN  = 2048;
constexpr int Bsz    = 64;
constexpr int Dd     = 128;
constexpr int Hh     = 128;
constexpr int Gg     = 512;
constexpr int XS     = 136;    // bf16 LDS row stride (producer A-tile / fallback)
constexpr int NCHUNK = 256;    // 8 timesteps per chunk
constexpr int CONS   = 64;     // consumer WGs (one per batch row)
constexpr int PROD   = 192;    // producer WGs
constexpr unsigned int SENT = 0x5EC7C0DEu;

typedef __attribute__((ext_vector_type(8))) short   short8;
typedef __attribute__((ext_vector_type(4))) float   floatx4;
typedef __attribute__((ext_vector_type(4))) int     intx4;
typedef __attribute__((ext_vector_type(2))) unsigned int uintx2;

#define MFMA16(a, b, c) __builtin_amdgcn_mfma_f32_16x16x32_bf16((a), (b), (c), 0, 0, 0)

#if __has_builtin(__builtin_amdgcn_sdot4)
__device__ __forceinline__ int dot4i8(int a, int b, int c) {
    return __builtin_amdgcn_sdot4(a, b, c, false);
}
#else
__device__ __forceinline__ int dot4i8(int a, int b, int c) {
#pragma unroll
    for (int j = 0; j < 4; ++j)
        c += ((a << (24 - 8 * j)) >> 24) * ((b << (24 - 8 * j)) >> 24);
    return c;
}
#endif

// value from partner lane^1 (quad_perm [1,0,3,2]) -- full-rate VALU
__device__ __forceinline__ int xor1_i(int v) {
    return __builtin_amdgcn_mov_dpp(v, 0xB1, 0xF, 0xF, true);
}

__device__ __forceinline__ float sigmoidf_(float x) {
    return __builtin_amdgcn_rcpf(1.0f + __builtin_amdgcn_exp2f(x * -1.44269504f));
}
__device__ __forceinline__ float tanhf_(float x) {
    return __builtin_fmaf(-2.0f,
        __builtin_amdgcn_rcpf(1.0f + __builtin_amdgcn_exp2f(x * 2.88539008f)), 1.0f);
}
__device__ __forceinline__ unsigned short f2bf(float f) {
    __hip_bfloat16 h = __float2bfloat16(f);  // RNE
    union { __hip_bfloat16 b; unsigned short u; } v; v.b = h; return v.u;
}
__device__ __forceinline__ float fi_(unsigned int u) {
    union { unsigned int u; float f; } v; v.u = u; return v.f;
}
__device__ __forceinline__ uintx2 f4bf(const float4 v) {
    union { unsigned short us[4]; uintx2 u2; } p;
    p.us[0] = f2bf(v.x); p.us[1] = f2bf(v.y); p.us[2] = f2bf(v.z); p.us[3] = f2bf(v.w);
    return p.u2;
}
__device__ __forceinline__ short8 ld8bf(const float* p) {
    const float4 a = *reinterpret_cast<const float4*>(p);
    const float4 b = *reinterpret_cast<const float4*>(p + 4);
    short8 s;
    s[0] = (short)f2bf(a.x); s[1] = (short)f2bf(a.y);
    s[2] = (short)f2bf(a.z); s[3] = (short)f2bf(a.w);
    s[4] = (short)f2bf(b.x); s[5] = (short)f2bf(b.y);
    s[6] = (short)f2bf(b.z); s[7] = (short)f2bf(b.w);
    return s;
}
// barrier without the compiler's vmcnt(0) drain: LDS-visibility only
__device__ __forceinline__ void lds_barrier() {
    asm volatile("s_waitcnt lgkmcnt(0)\n\ts_barrier" ::: "memory");
}
__device__ __forceinline__ void wait_chunk(const unsigned int* flags, int k) {
    while (__hip_atomic_load(&flags[k], __ATOMIC_RELAXED,
                             __HIP_MEMORY_SCOPE_AGENT) != SENT)
        __builtin_amdgcn_s_sleep(2);
    __builtin_amdgcn_fence(__ATOMIC_ACQUIRE, "agent");
}

// =================== fused producer/consumer kernel ==========================
__global__ __launch_bounds__(256) void lstm_fused_all(
    const int*   __restrict__ tokens,
    const float* __restrict__ emb,
    const float* __restrict__ Wih,
    const float* __restrict__ Whh,
    const float* __restrict__ bih,
    const float* __restrict__ bhh,
    unsigned short* __restrict__ xg,     // [T][64][128][4] bf16, in d_ws
    unsigned int*   __restrict__ flags,  // [NCHUNK], in d_ws after xg
    float*       __restrict__ out)       // [2][64][128] fp32
{
    __shared__ __align__(16) unsigned short albs[2][64 * XS];  // producer A-tile

    const int tid = threadIdx.x;

    if (blockIdx.x < CONS) {
        // ================= CONSUMER: one batch row ===========================
        signed char (*hbuf)[128] =
            reinterpret_cast<signed char (*)[128]>(&albs[0][0]);  // [2][128]

        const int wv = tid >> 6;          // wave 0..3
        const int l  = tid & 63;
        const int kh = l & 1;             // K half (0: k<64, 1: k>=64)
        const int c  = wv * 32 + (l >> 1);  // hidden column
        const int b  = blockIdx.x;        // batch row

        // Whh rows {g*128+c} -> i8 (full-row scale; quantize own K-half)
        int   wq[4][16];
        float dq[4];
#pragma unroll
        for (int g = 0; g < 4; ++g) {
            const float* wr = Whh + (size_t)(g * 128 + c) * Hh;
            float am = 0.f;
#pragma unroll 8
            for (int k = 0; k < 128; k += 4) {
                const float4 v = *reinterpret_cast<const float4*>(wr + k);
                am = fmaxf(am, fmaxf(fmaxf(fabsf(v.x), fabsf(v.y)),
                                     fmaxf(fabsf(v.z), fabsf(v.w))));
            }
            const float swm = fmaxf(am, 1e-20f);
            dq[g] = swm * (1.0f / (127.0f * 127.0f));
            const float inv = 127.0f / swm;
#pragma unroll
            for (int d = 0; d < 16; ++d) {
                const float4 v =
                    *reinterpret_cast<const float4*>(wr + kh * 64 + d * 4);
                const int b0 = (int)__builtin_rintf(v.x * inv);
                const int b1 = (int)__builtin_rintf(v.y * inv);
                const int b2 = (int)__builtin_rintf(v.z * inv);
                const int b3 = (int)__builtin_rintf(v.w * inv);
                wq[g][d] = (b0 & 0xff) | ((b1 & 0xff) << 8) |
                           ((b2 & 0xff) << 16) | ((b3 & 0xff) << 24);
            }
        }

        // h(0) = 0 in regs (buffers always written before read)
        intx4 hv[4];
#pragma unroll
        for (int j = 0; j < 4; ++j) hv[j] = (intx4){0, 0, 0, 0};

        const unsigned short* xptr = xg + (size_t)b * Gg + c * 4;
        const size_t xstride = (size_t)Bsz * Gg;

        // startup: verify chunks 0 and 1; load chunk 0
        wait_chunk(flags, 0);
        uintx2 xc[8], xcn[8];
#pragma unroll
        for (int u = 0; u < 8; ++u)
            xc[u] = *reinterpret_cast<const uintx2*>(xptr + (size_t)u * xstride);
        wait_chunk(flags, 1);

        float c_state = 0.0f;
        float h_last  = 0.0f;

        for (int g = 0; g < NCHUNK; ++g) {
#pragma unroll
            for (int s = 0; s < 8; ++s) {
                if (s == 0) {
                    // flag[g+1] verified a chunk ago -> load immediately
                    int tn = g + 1;
                    if (tn >= NCHUNK) tn = 0;       // dummy re-load of chunk 0
                    const size_t tb = (size_t)tn * 8;
#pragma unroll
                    for (int u = 0; u < 8; ++u)
                        xcn[u] = *reinterpret_cast<const uintx2*>(
                            xptr + (tb + u) * xstride);
                }
                if (s == 4) {
                    // distance-2 flag poll, off the load-burst slot
                    if (g + 2 < NCHUNK) wait_chunk(flags, g + 2);
                }

                // half-gates: two independent 8-deep sdot4 chains per gate
                int a0 = 0, a1 = 0, a2 = 0, a3 = 0;
                int b0 = 0, b1 = 0, b2 = 0, b3 = 0;
#pragma unroll
                for (int j = 0; j < 2; ++j) {
#pragma unroll
                    for (int e = 0; e < 4; ++e) {
                        const int hd = hv[j][e];
                        const int d  = j * 4 + e;
                        a0 = dot4i8(wq[0][d], hd, a0);
                        a1 = dot4i8(wq[1][d], hd, a1);
                        a2 = dot4i8(wq[2][d], hd, a2);
                        a3 = dot4i8(wq[3][d], hd, a3);
                    }
                }
#pragma unroll
                for (int j = 2; j < 4; ++j) {
#pragma unroll
                    for (int e = 0; e < 4; ++e) {
                        const int hd = hv[j][e];
                        const int d  = j * 4 + e;
                        b0 = dot4i8(wq[0][d], hd, b0);
                        b1 = dot4i8(wq[1][d], hd, b1);
                        b2 = dot4i8(wq[2][d], hd, b2);
                        b3 = dot4i8(wq[3][d], hd, b3);
                    }
                }
                const int s0 = a0 + b0, s1 = a1 + b1;
                const int s2 = a2 + b2, s3 = a3 + b3;
                // merge K-halves with partner lane^1 (DPP, no LDS)
                const int m0 = s0 + xor1_i(s0);
                const int m1 = s1 + xor1_i(s1);
                const int m2 = s2 + xor1_i(s2);
                const int m3 = s3 + xor1_i(s3);

                const uintx2 xv = xc[s];
                const float iv = (float)m0 * dq[0] + fi_(xv.x << 16);
                const float fv = (float)m1 * dq[1] + fi_(xv.x & 0xffff0000u);
                const float gv = (float)m2 * dq[2] + fi_(xv.y << 16);
                const float ov = (float)m3 * dq[3] + fi_(xv.y & 0xffff0000u);
                const float si = sigmoidf_(iv);
                const float sf = sigmoidf_(fv);
                const float so = sigmoidf_(ov);
                const float tg = tanhf_(gv);
                c_state = __builtin_fmaf(sf, c_state, si * tg);
                h_last  = so * tanhf_(c_state);

                const int nxt = (s & 1) ^ 1;        // buffer parity of t+1
                if (kh == 0)
                    hbuf[nxt][c] =
                        (signed char)((int)__builtin_rintf(h_last * 127.0f));
                if (s == 7) {
#pragma unroll
                    for (int u = 0; u < 8; ++u) xc[u] = xcn[u];
                }
                lds_barrier();  // lgkm-only: h visible, vmem stays in flight
#pragma unroll
                for (int j = 0; j < 4; ++j)
                    hv[j] = *reinterpret_cast<const intx4*>(
                        &hbuf[nxt][kh * 64 + j * 16]);
            }
        }

        if (kh == 0) {
            out[b * Hh + c]            = h_last;
            out[Bsz * Hh + b * Hh + c] = c_state;
        }
    } else {
        // ================= PRODUCER: xg chunks of 8 timesteps ================
        const int pid  = blockIdx.x - CONS;
        const int wv   = tid >> 6;
        const int l    = tid & 63;
        const int quad = l >> 4;
        const int cl   = l & 15;
        const int srow = tid >> 2, sseg = tid & 3;   // staging: row, 32-col seg

        // bias for this lane's two hh columns (j = wv*2 + jj)
        float bias[2][4];
#pragma unroll
        for (int jj = 0; jj < 2; ++jj) {
            const int hhj = (wv * 2 + jj) * 16 + cl;
#pragma unroll
            for (int g = 0; g < 4; ++g)
                bias[jj][g] = bih[g * 128 + hhj] + bhh[g * 128 + hhj];
        }

        for (int chunk = pid; chunk < NCHUNK; chunk += PROD) {
            const int t0 = chunk * 8;

            {   // stage t0 into buf 0
                const int tok = tokens[srow * T_LEN + t0];
                const float* src = emb + (size_t)tok * Dd + sseg * 32;
#pragma unroll
                for (int p = 0; p < 4; ++p)
                    *reinterpret_cast<short8*>(
                        &albs[0][srow * XS + sseg * 32 + p * 8]) = ld8bf(src + p * 8);
            }
            __syncthreads();

            for (int tt = 0; tt < 8; ++tt) {
                const int cur = tt & 1, nxt = cur ^ 1;
                if (tt < 7) {   // stage next t
                    const int tok = tokens[srow * T_LEN + t0 + tt + 1];
                    const float* src = emb + (size_t)tok * Dd + sseg * 32;
#pragma unroll
                    for (int p = 0; p < 4; ++p)
                        *reinterpret_cast<short8*>(
                            &albs[nxt][srow * XS + sseg * 32 + p * 8]) =
                            ld8bf(src + p * 8);
                }

                // A-fragments for all 4 m-tiles x 4 k-chunks
                short8 af[4][4];
#pragma unroll
                for (int m = 0; m < 4; ++m)
#pragma unroll
                    for (int k = 0; k < 4; ++k)
                        af[m][k] = *reinterpret_cast<const short8*>(
                            &albs[cur][(m * 16 + cl) * XS + k * 32 + quad * 8]);

                const int t = t0 + tt;
#pragma unroll
                for (int jj = 0; jj < 2; ++jj) {
                    const int hhj = (wv * 2 + jj) * 16 + cl;
                    floatx4 acc[4][4];  // [g][m]
#pragma unroll
                    for (int g = 0; g < 4; ++g)
#pragma unroll
                        for (int m = 0; m < 4; ++m)
                            acc[g][m] = (floatx4){0.f, 0.f, 0.f, 0.f};
#pragma unroll
                    for (int g = 0; g < 4; ++g) {
                        const int n = g * 128 + hhj;
                        short8 bf[4];
#pragma unroll
                        for (int k = 0; k < 4; ++k)
                            bf[k] = ld8bf(Wih + (size_t)n * Dd + k * 32 + quad * 8);
#pragma unroll
                        for (int k = 0; k < 4; ++k)
#pragma unroll
                            for (int m = 0; m < 4; ++m)
                                acc[g][m] = MFMA16(af[m][k], bf[k], acc[g][m]);
                    }
                    // pack 4 gates per (b-row) and store 8 B
#pragma unroll
                    for (int m = 0; m < 4; ++m) {
#pragma unroll
                        for (int r = 0; r < 4; ++r) {
                            const int brow = m * 16 + quad * 4 + r;
                            union { unsigned short us[4]; uintx2 u2; } p;
#pragma unroll
                            for (int g = 0; g < 4; ++g)
                                p.us[g] = f2bf(acc[g][m][r] + bias[jj][g]);
                            *reinterpret_cast<uintx2*>(
                                xg + ((size_t)t * Bsz + brow) * Gg + hhj * 4) =
                                p.u2;
                        }
                    }
                }
                __syncthreads();  // staged buf visible; stores drained (vmcnt0)
            }

            // release: all 256 threads' stores are complete (barrier drained)
            if (tid == 0) {
                __builtin_amdgcn_fence(__ATOMIC_RELEASE, "agent");
                __hip_atomic_store(&flags[chunk], SENT, __ATOMIC_RELAXED,
                                   __HIP_MEMORY_SCOPE_AGENT);
            }
        }
    }
}

// ---------------- Fallback (R2 working kernel) if ws too small ---------------
__global__ __launch_bounds__(512, 2) void lstm_fused_fb(
    const int*   __restrict__ tokens,
    const float* __restrict__ emb,
    const float* __restrict__ Wih,
    const float* __restrict__ Whh,
    const float* __restrict__ bih,
    const float* __restrict__ bhh,
    float*       __restrict__ out)
{
    __shared__ unsigned short xbuf[2][16 * XS];
    __shared__ unsigned short hbuf2[2][16 * XS];
    __shared__ float scratch[4 * Gg];

    const int tid  = threadIdx.x;
    const int w    = tid >> 6;
    const int l    = tid & 63;
    const int quad = l >> 4;
    const int cl   = l & 15;
    const int bbase = blockIdx.x * 4;
    const int rr = tid >> 7;
    const int hh = tid & 127;

    short8 wih[4][4], whh[4][4];
    float  bias[4];
#pragma unroll
    for (int q = 0; q < 4; ++q) {
        const int n = q * 128 + w * 16 + cl;
#pragma unroll
        for (int kk = 0; kk < 4; ++kk) {
            const int k0 = kk * 32 + quad * 8;
            wih[q][kk] = ld8bf(Wih + n * Dd + k0);
            whh[q][kk] = ld8bf(Whh + n * Hh + k0);
        }
        bias[q] = bih[n] + bhh[n];
    }

    for (int i = tid; i < 16 * XS; i += 512) {
        xbuf[0][i] = 0; xbuf[1][i] = 0; hbuf2[0][i] = 0; hbuf2[1][i] = 0;
    }

    const bool gact = (tid < 128);
    const int  gr = tid >> 5;
    const int  gp = tid & 31;
    float4 gdataf = {0.f, 0.f, 0.f, 0.f};
    if (gact) {
        const int tok = tokens[(bbase + gr) * T_LEN + 0];
        gdataf = *reinterpret_cast<const float4*>(emb + (size_t)tok * Dd + gp * 4);
    }
    __syncthreads();
    if (gact) *reinterpret_cast<uintx2*>(&xbuf[0][gr * XS + gp * 4]) = f4bf(gdataf);
    if (gact) {
        const int tok = tokens[(bbase + gr) * T_LEN + 1];
        gdataf = *reinterpret_cast<const float4*>(emb + (size_t)tok * Dd + gp * 4);
    }
    __syncthreads();

    const int afrag_el = cl * XS + quad * 8;

    floatx4 acc[4];
#pragma unroll
    for (int q = 0; q < 4; ++q) acc[q] = (floatx4){bias[q], bias[q], bias[q], bias[q]};
    {
        short8 xf[4];
#pragma unroll
        for (int kk = 0; kk < 4; ++kk)
            xf[kk] = *reinterpret_cast<const short8*>(&xbuf[0][afrag_el + kk * 32]);
#pragma unroll
        for (int kk = 0; kk < 4; ++kk)
#pragma unroll
            for (int q = 0; q < 4; ++q)
                acc[q] = MFMA16(xf[kk], wih[q][kk], acc[q]);
    }

    float c_state = 0.0f, h_last = 0.0f;

    for (int t = 0; t < T_LEN; ++t) {
        const int cur = t & 1, nxt = cur ^ 1;
        short8 hf[4];
#pragma unroll
        for (int kk = 0; kk < 4; ++kk)
            hf[kk] = *reinterpret_cast<const short8*>(&hbuf2[cur][afrag_el + kk * 32]);
        if (gact && (t + 1 < T_LEN))
            *reinterpret_cast<uintx2*>(&xbuf[nxt][gr * XS + gp * 4]) = f4bf(gdataf);
        if (gact && (t + 2 < T_LEN)) {
            const int tok = tokens[(bbase + gr) * T_LEN + (t + 2)];
            gdataf = *reinterpret_cast<const float4*>(emb + (size_t)tok * Dd + gp * 4);
        }
#pragma unroll
        for (int kk = 0; kk < 4; ++kk)
#pragma unroll
            for (int q = 0; q < 4; ++q)
                acc[q] = MFMA16(hf[kk], whh[q][kk], acc[q]);
        if (quad == 0) {
#pragma unroll
            for (int q = 0; q < 4; ++q) {
                const int n = q * 128 + w * 16 + cl;
#pragma unroll
                for (int r = 0; r < 4; ++r)
                    scratch[r * Gg + n] = acc[q][r];
            }
        }
        __syncthreads();
#pragma unroll
        for (int q = 0; q < 4; ++q) acc[q] = (floatx4){bias[q], bias[q], bias[q], bias[q]};
        if (t + 1 < T_LEN) {
            short8 xf[4];
#pragma unroll
            for (int kk = 0; kk < 4; ++kk)
                xf[kk] = *reinterpret_cast<const short8*>(&xbuf[nxt][afrag_el + kk * 32]);
#pragma unroll
            for (int kk = 0; kk < 4; ++kk)
#pragma unroll
                for (int q = 0; q < 4; ++q)
                    acc[q] = MFMA16(xf[kk], wih[q][kk], acc[q]);
        }
        {
            const float iv = scratch[rr * Gg + hh];
            const float fv = scratch[rr * Gg + 128 + hh];
            const float gv = scratch[rr * Gg + 256 + hh];
            const float ov = scratch[rr * Gg + 384 + hh];
            const float si = sigmoidf_(iv);
            const float sf = sigmoidf_(fv);
            const float so = sigmoidf_(ov);
            const float tg = tanhf_(gv);
            c_state = sf * c_state + si * tg;
            h_last  = so * tanhf_(c_state);
            hbuf2[nxt][rr * XS + hh] = f2bf(h_last);
        }
        __syncthreads();
    }

    const int ob = (bbase + rr) * Hh + hh;
    out[ob]            = h_last;
    out[Bsz * Hh + ob] = c_state;
}

}  // namespace

extern "C" void kernel_launch(void* const* d_in, const int* in_sizes, int n_in,
                              void* d_out, int out_size, void* d_ws, size_t ws_size,
                              hipStream_t stream) {
    (void)in_sizes; (void)n_in; (void)out_size;
    const int*   tokens = (const int*)d_in[0];
    const float* emb    = (const float*)d_in[1];
    const float* Wih    = (const float*)d_in[2];
    const float* Whh    = (const float*)d_in[3];
    const float* bih    = (const float*)d_in[4];
    const float* bhh    = (const float*)d_in[5];

    const size_t xg_bytes = (size_t)T_LEN * Bsz * Gg * sizeof(unsigned short);  // 134 MB
    const size_t need = xg_bytes + NCHUNK * sizeof(unsigned int);
    if (ws_size >= need) {
        unsigned short* xg    = (unsigned short*)d_ws;
        unsigned int*   flags = (unsigned int*)((char*)d_ws + xg_bytes);
        lstm_fused_all<<<CONS + PROD, 256, 0, stream>>>(
            tokens, emb, Wih, Whh, bih, bhh, xg, flags, (float*)d_out);
    } else {
        lstm_fused_fb<<<16, 512, 0, stream>>>(tokens, emb, Wih, Whh, bih, bhh,
                                              (float*)d_out);
    }
}